// Round 8
// baseline (107.883 us; speedup 1.0000x reference)
//
#include <hip/hip_runtime.h>
#include <math.h>

// Problem sizes (fixed by setup_inputs)
constexpr int BATCH = 64;
constexpr int IN    = 1024;
constexpr int NN    = 2048;   // num_neurons
constexpr int OUTF  = 1024;

constexpr float INV2PI = 0.15915494309189535f;  // 1/(2*pi)
constexpr float SQRT2  = 1.4142135623730951f;

// sin_t + cos_t = sqrt(2)*sin(theta + pi/4); reference LUT-quantizes theta to
// 2pi/4096 steps. We drop the quantization (|err| <= sqrt2*pi/4096 ~ 1.1e-3
// per element -> ~8 absmax on the output vs threshold 26.7), so each element
// is ONE fma + ONE v_sin: a = x*(rcp(1+|W|)/2pi) + (B/2pi + 1/8) [revolutions].

// Butterfly transpose-reduction with COMPILE-TIME trip counts.
// (Runtime inner bound -> dynamic acc[] index -> SROA fails -> acc in
//  scratch: rounds 1-3 lost 300MB of HBM to that.)
template<int M>
__device__ __forceinline__ void butterfly(float* acc, int lane) {
    const bool hi = (lane & M) != 0;
#pragma unroll
    for (int j = 0; j < M; ++j) {
        const float send = hi ? acc[j] : acc[j + M];
        const float recv = __shfl_xor(send, M, 64);
        acc[j] = (hi ? acc[j + M] : acc[j]) + recv;
    }
    if constexpr (M > 1) butterfly<M / 2>(acc, lane);
}

// ---------------- Stage 1: interference ---------------- (UNCHANGED: control)
// part[b][n] fp32, 64 x 2048 = 512KB, transposed so stage 2 reads along n.

__global__ __launch_bounds__(512)
__attribute__((amdgpu_waves_per_eu(4, 4)))
void k_interf(const float* __restrict__ x, const float* __restrict__ W,
              const float* __restrict__ B, float* __restrict__ part) {
    __shared__ float xs[2][32 * 256];   // double buffer, 2 x 32KB

    const int tid  = threadIdx.x;
    const int lane = tid & 63;
    const int wv   = __builtin_amdgcn_readfirstlane(tid >> 6);   // 0..7
    const int bid  = blockIdx.x;      // 512 blocks
    const int h    = bid & 1;         // batch half
    const int n    = (bid >> 1) * 8 + wv;

    float4 iv2[4], bs2[4];
#pragma unroll
    for (int kc = 0; kc < 4; ++kc) {
        const float4 w4 = *(const float4*)&W[(size_t)n * IN + kc * 256 + 4 * lane];
        const float4 b4 = *(const float4*)&B[(size_t)n * IN + kc * 256 + 4 * lane];
        iv2[kc].x = INV2PI * __builtin_amdgcn_rcpf(1.0f + fabsf(w4.x));
        iv2[kc].y = INV2PI * __builtin_amdgcn_rcpf(1.0f + fabsf(w4.y));
        iv2[kc].z = INV2PI * __builtin_amdgcn_rcpf(1.0f + fabsf(w4.z));
        iv2[kc].w = INV2PI * __builtin_amdgcn_rcpf(1.0f + fabsf(w4.w));
        bs2[kc].x = fmaf(b4.x, INV2PI, 0.125f);
        bs2[kc].y = fmaf(b4.y, INV2PI, 0.125f);
        bs2[kc].z = fmaf(b4.z, INV2PI, 0.125f);
        bs2[kc].w = fmaf(b4.w, INV2PI, 0.125f);
    }

    const float* gx = x + (size_t)(h * 32) * IN;   // this block's 32 batch rows

#define STAGE(KC, P)                                                           \
    {                                                                          \
        _Pragma("unroll")                                                      \
        for (int rr = 0; rr < 4; ++rr) {                                       \
            const int r = wv * 4 + rr;  /* wave-uniform LDS base */            \
            __builtin_amdgcn_global_load_lds(                                  \
                (const __attribute__((address_space(1))) unsigned int*)        \
                    (gx + (size_t)r * IN + (KC) * 256 + 4 * lane),             \
                (__attribute__((address_space(3))) unsigned int*)              \
                    &xs[(P)][r * 256],                                         \
                16, 0, 0);                                                     \
        }                                                                      \
    }

    float acc[32];
#pragma unroll
    for (int j = 0; j < 32; ++j) acc[j] = 0.0f;

    STAGE(0, 0);
    __syncthreads();   // chunk 0 ready (vmcnt drain + barrier)

#pragma unroll
    for (int kc = 0; kc < 4; ++kc) {
        const int p = kc & 1;
        if (kc < 3) STAGE(kc + 1, 1 - p);   // prefetch rides over this chunk's compute

        const float4 iv = iv2[kc], bs = bs2[kc];
#pragma unroll   // MUST be full: partial unroll -> dynamic acc idx -> scratch
        for (int bb = 0; bb < 32; ++bb) {
            const float4 xv = *(const float4*)&xs[p][bb * 256 + 4 * lane];
            const float a0 = fmaf(xv.x, iv.x, bs.x);
            const float a1 = fmaf(xv.y, iv.y, bs.y);
            const float a2 = fmaf(xv.z, iv.z, bs.z);
            const float a3 = fmaf(xv.w, iv.w, bs.w);
            const float t0 = __builtin_amdgcn_sinf(a0);   // sin(2*pi*a)
            const float t1 = __builtin_amdgcn_sinf(a1);
            const float t2 = __builtin_amdgcn_sinf(a2);
            const float t3 = __builtin_amdgcn_sinf(a3);
            acc[bb] += (t0 + t1) + (t2 + t3);
        }
        __syncthreads();   // drains long-in-flight prefetch; frees buf p
    }
#undef STAGE

    // transpose-reduce 32 values over 64 lanes -> lane l (<32) holds batch h*32+l
#pragma unroll
    for (int j = 0; j < 32; ++j) acc[j] += __shfl_xor(acc[j], 32, 64);
    butterfly<16>(acc, lane);

    if (lane < 32)   // scattered store into transposed part[b][n]
        part[(size_t)(h * 32 + lane) * NN + n] = acc[0] * SQRT2;
}

// ---------------- Stage 2: projection ----------------
// out[b][o] = sum_n part[b][n] * ow[o][n]. Wave owns 4o x 8b, lane spans n.
// v2 changes vs round 7:
//  (1) XCD-resident tiling: bid&7 (dispatch round-robins XCDs) picks a 128-wide
//      o-group -> per-XCD working set = 1MB ow + 0.5MB part < 4MB L2. Round-7's
//      arbitrary assignment streamed most of the 8MB ow through every XCD's L2
//      -> HBM misses at ~900cyc with only 2 waves/SIMD to hide them.
//  (2) Fully unrolled slab loop (no stores inside, __restrict__): lets the
//      compiler hoist/pipeline the 96 independent float4 loads under the
//      256-VGPR budget instead of 8 serial load->wait->fma rounds.

__global__ __launch_bounds__(256)
__attribute__((amdgpu_waves_per_eu(2, 2)))   // 256-VGPR budget: acc 128 + operands
void k_proj(const float* __restrict__ part, const float* __restrict__ ow,
            float* __restrict__ out) {
    const int tid  = threadIdx.x;
    const int lane = tid & 63;
    const int wv   = __builtin_amdgcn_readfirstlane(tid >> 6);
    const int bid  = blockIdx.x;              // 512 blocks
    const int g    = bid & 7;                 // XCD-local o-group (8 groups of 128 o)
    const int inr  = bid >> 3;                // 0..63
    const int o0   = g * 128 + (inr & 7) * 16 + wv * 4;   // wave's 4 o-rows
    const int b0   = (inr >> 3) * 8;                      // wave's 8 b-rows

    float4 acc[4][8];
#pragma unroll
    for (int o = 0; o < 4; ++o)
#pragma unroll
        for (int b = 0; b < 8; ++b) acc[o][b] = make_float4(0.f, 0.f, 0.f, 0.f);

#pragma unroll   // full: exposes all 96 loads for cross-slab pipelining
    for (int it = 0; it < NN / 256; ++it) {   // 8 slabs of 256 n
        const int nb = it * 256 + lane * 4;
        float4 wrow[4], vrow[8];
#pragma unroll
        for (int o = 0; o < 4; ++o)
            wrow[o] = *(const float4*)&ow[(size_t)(o0 + o) * NN + nb];
#pragma unroll
        for (int b = 0; b < 8; ++b)
            vrow[b] = *(const float4*)&part[(size_t)(b0 + b) * NN + nb];
#pragma unroll
        for (int o = 0; o < 4; ++o)
#pragma unroll
            for (int b = 0; b < 8; ++b) {
                acc[o][b].x = fmaf(wrow[o].x, vrow[b].x, acc[o][b].x);
                acc[o][b].y = fmaf(wrow[o].y, vrow[b].y, acc[o][b].y);
                acc[o][b].z = fmaf(wrow[o].z, vrow[b].z, acc[o][b].z);
                acc[o][b].w = fmaf(wrow[o].w, vrow[b].w, acc[o][b].w);
            }
    }

    // horizontal: 32 scalars, accs[o*8+b]
    float accs[32];
#pragma unroll
    for (int o = 0; o < 4; ++o)
#pragma unroll
        for (int b = 0; b < 8; ++b)
            accs[o * 8 + b] = (acc[o][b].x + acc[o][b].y) + (acc[o][b].z + acc[o][b].w);

    // cross-lane sum over all 64 lanes; lane l<32 ends with tile-element l's total
#pragma unroll
    for (int j = 0; j < 32; ++j) accs[j] += __shfl_xor(accs[j], 32, 64);
    butterfly<16>(accs, lane);

    if (lane < 32)   // j = o*8+b  ->  o = lane>>3, b = lane&7
        out[(size_t)(b0 + (lane & 7)) * OUTF + o0 + (lane >> 3)] = accs[0];
}

extern "C" void kernel_launch(void* const* d_in, const int* in_sizes, int n_in,
                              void* d_out, int out_size, void* d_ws, size_t ws_size,
                              hipStream_t stream) {
    const float* x  = (const float*)d_in[0];
    const float* W  = (const float*)d_in[1];
    const float* B  = (const float*)d_in[2];
    const float* ow = (const float*)d_in[3];
    float* out  = (float*)d_out;
    float* part = (float*)d_ws;    // 512 KB, [b][n] transposed

    k_interf<<<dim3(512), dim3(512), 0, stream>>>(x, W, B, part);
    k_proj  <<<dim3(512), dim3(256), 0, stream>>>(part, ow, out);
}